// Round 12
// baseline (2516.792 us; speedup 1.0000x reference)
//
#include <hip/hip_runtime.h>
#include <hip/hip_fp16.h>

#define B_   16
#define T_   4096
#define DIN  256
#define H_   128
#define G3   384   // 3*H

// exponent prescales: sigmoid -> rcp(1+exp2(-log2e * x)), tanh via sigmoid(2x)
#define SC_RZ 1.4426950408889634f
#define SC_N  2.8853900817779268f

typedef _Float16 half2_t __attribute__((ext_vector_type(2)));

__device__ __forceinline__ float fdot2(unsigned int a, unsigned int b, float c) {
#if __has_builtin(__builtin_amdgcn_fdot2)
  return __builtin_amdgcn_fdot2(__builtin_bit_cast(half2_t, a),
                                __builtin_bit_cast(half2_t, b), c, false);
#else
  const __half2 ha = __builtin_bit_cast(__half2, a);
  const __half2 hb = __builtin_bit_cast(__half2, b);
  return c + __half2float(__low2half(ha)) * __half2float(__low2half(hb))
           + __half2float(__high2half(ha)) * __half2float(__high2half(hb));
#endif
}

// Cross-lane add via DPP quad_perm (pure VALU — no LDS pipe):
// CTRL 0xB1 = quad_perm [1,0,3,2] (lane^1), 0x4E = [2,3,0,1] (lane^2).
template <int CTRL>
__device__ __forceinline__ float dpp_xor_add(float x) {
  const int yi = __builtin_amdgcn_mov_dpp(__builtin_bit_cast(int, x),
                                          CTRL, 0xF, 0xF, true);
  return x + __builtin_bit_cast(float, yi);
}

__device__ __forceinline__ unsigned int pack2(float x, float y) {
  __half2 h = __floats2half2_rn(x, y);
  return __builtin_bit_cast(unsigned int, h);
}

__device__ __forceinline__ float fexp2(float x) {
#if __has_builtin(__builtin_amdgcn_exp2f)
  return __builtin_amdgcn_exp2f(x);
#else
  return exp2f(x);
#endif
}
__device__ __forceinline__ float frcp(float x) {
#if __has_builtin(__builtin_amdgcn_rcpf)
  return __builtin_amdgcn_rcpf(x);
#else
  return 1.f / x;
#endif
}

// lgkmcnt-only barrier: LDS ordering without draining global loads/stores.
__device__ __forceinline__ void scan_barrier() {
  asm volatile("s_waitcnt lgkmcnt(0)" ::: "memory");
  __builtin_amdgcn_s_barrier();
  asm volatile("" ::: "memory");
}

__device__ __forceinline__ void barrier_lds() {
  asm volatile("s_waitcnt lgkmcnt(0)" ::: "memory");
  __builtin_amdgcn_s_barrier();
  asm volatile("" ::: "memory");
}

__device__ __forceinline__ void wave_lds_fence() {
  asm volatile("s_waitcnt lgkmcnt(0)" ::: "memory");
}

// ---------------------------------------------------------------------------
// Kernel 1: gi[r, j] = f16( b_ih[j] + (j<256 ? b_hh[j] : 0) + dot(x,w_ih[j]) )
// b_hh fold is legal ONLY for r,z rows: torch computes
//   n = tanh(inn + b_in + r*(W_hn.h + b_hn))  -- b_hn stays under r.
// ---------------------------------------------------------------------------
__global__ __launch_bounds__(384, 1) void gi_gemm(
    const float* __restrict__ x, const float* __restrict__ w_ih,
    const float* __restrict__ b_ih, const float* __restrict__ b_hh,
    __half* __restrict__ gi) {
  const int j = threadIdx.x;             // 0..383 : output gate-row
  const int rbase = blockIdx.x * 128;    // 128 x-rows per block

  unsigned int wreg[128];                // 256 halves = w_ih row j
  const float* wrow = w_ih + (size_t)j * DIN;
#pragma unroll
  for (int k = 0; k < 128; ++k) {
    float2 w2 = reinterpret_cast<const float2*>(wrow)[k];
    wreg[k] = pack2(w2.x, w2.y);
  }
  const float bias = b_ih[j] + ((j < 256) ? b_hh[j] : 0.f);

  __shared__ alignas(16) unsigned int xs[16 * 128];  // 16 rows x 256 halves

  for (int c = 0; c < 8; ++c) {          // 8 chunks of 16 rows
    barrier_lds();                       // protect xs vs previous chunk reads
    const int row0 = rbase + c * 16;
    for (int i = j; i < 16 * 128; i += 384) {
      const int r = i >> 7, col = i & 127;
      float2 v = reinterpret_cast<const float2*>(x + (size_t)(row0 + r) * DIN)[col];
      xs[i] = pack2(v.x, v.y);
    }
    barrier_lds();
    for (int r = 0; r < 16; ++r) {
      float a0 = 0.f, a1 = 0.f, a2 = 0.f, a3 = 0.f;
      const uint4* hp = reinterpret_cast<const uint4*>(xs + r * 128);
#pragma unroll
      for (int k = 0; k < 32; ++k) {
        uint4 hv = hp[k];                // uniform addr -> LDS broadcast
        a0 = fdot2(wreg[4 * k + 0], hv.x, a0);
        a1 = fdot2(wreg[4 * k + 1], hv.y, a1);
        a2 = fdot2(wreg[4 * k + 2], hv.z, a2);
        a3 = fdot2(wreg[4 * k + 3], hv.w, a3);
      }
      const float acc = bias + ((a0 + a1) + (a2 + a3));
      gi[(size_t)(row0 + r) * G3 + j] = __float2half(acc);
    }
  }
}

// ---------------------------------------------------------------------------
// Kernel 2: GRU scan. 16 blocks (1/batch) x 512 threads (8 waves, 2/SIMD).
// Lane (w, l): col c = w*16 + (l>>2), K-quarter kq = l&3.
// Dots via v_pk_fma_f16 (full-rate packed: 2 MACs / 2 cyc — 2x the f32 rate);
// per-lane f16 accumulation (8-deep chains; R9-vs-R8 evidence: f16 accum
// contributes ~1e-3 absmax), pair-sum in f16, widened to f32, combined across
// the quad via DPP adds. Recurrence state hp stays f32. h broadcast f16 in
// double-buffered LDS (quarters strided 72 B -> conflict-free b128 reads).
// b_hn folded into the n-acc init of kq==0 lanes (exact). Merged gate
// algebra: h = [hp(1+en) + ez(1-en)] / [(1+ez)(1+en)] -> 3 exp2 + 2 rcp.
// One lgkm-only barrier per step; gi prefetched 4 steps deep (named regs).
// ---------------------------------------------------------------------------
__global__ __launch_bounds__(512, 1) void gru_scan(
    const __half* __restrict__ gi, const float* __restrict__ w_hh,
    const float* __restrict__ b_hh, float* __restrict__ out) {
  const int b   = blockIdx.x;
  const int tid = threadIdx.x;
  const int l   = tid & 63;
  const int w   = tid >> 6;              // wave 0..7
  const int kq  = l & 3;                 // K-quarter 0..3
  const int c   = w * 16 + (l >> 2);     // hidden column 0..127

  // Weights: rows {c, 128+c, 256+c}, K-range [kq*32, kq*32+32), f16x2,
  // prescaled by -log2e (r,z) / -2log2e (n).
  __half2 wgt[3][16];
#pragma unroll
  for (int g = 0; g < 3; ++g) {
    const float sg = (g < 2) ? -SC_RZ : -SC_N;
    const float* row = w_hh + (size_t)(g * H_ + c) * H_ + kq * 32;
#pragma unroll
    for (int k = 0; k < 16; ++k) {
      float2 a = reinterpret_cast<const float2*>(row)[k];
      wgt[g][k] = __floats2half2_rn(a.x * sg, a.y * sg);
    }
  }
  // scaled b_hn, folded into the n-accumulator init of the kq==0 lane only
  // (exact: the quad-sum then contains bnS exactly once).
  const float bnS = b_hh[2 * H_ + c] * -SC_N;
  const __half2 initN = __floats2half2_rn((kq == 0) ? bnS : 0.f, 0.f);
  const __half2 z2h = __floats2half2_rn(0.f, 0.f);

  // h buffers (f16): quarter q (h[32q..32q+31], 64 B) at byte offset 72*q
  // (72 B stride -> the 4 broadcast addrs per b128 hit disjoint bank quads).
  __shared__ alignas(16) char hA[288];
  __shared__ alignas(16) char hB[288];
  if (tid < 72) reinterpret_cast<unsigned int*>(hA)[tid] = 0u;  // h0 = 0

  const int abase = kq * 72;             // this lane's K-quarter base (bytes)
  const int woff  = (c >> 5) * 72 + (c & 31) * 2;  // h write byte (kq==0)

  const __half* gp = gi + (size_t)b * T_ * G3;
  float* po = out + ((size_t)b * T_) * H_ + c;
  const int o0 = c, o1 = H_ + c, o2 = 2 * H_ + c;

  // 4-deep prefetch: raw __half regs (convert at use), statically named.
  __half pa0 = gp[o0],          pz0 = gp[o1],          pn0 = gp[o2];
  __half pa1 = gp[G3 + o0],     pz1 = gp[G3 + o1],     pn1 = gp[G3 + o2];
  __half pa2 = gp[2 * G3 + o0], pz2 = gp[2 * G3 + o1], pn2 = gp[2 * G3 + o2];
  __half pa3 = gp[3 * G3 + o0], pz3 = gp[3 * G3 + o1], pn3 = gp[3 * G3 + o2];
  const __half* r0 = gp + 4 * G3;        // refill sources, one per phase
  const __half* r1 = gp + 5 * G3;
  const __half* r2 = gp + 6 * G3;
  const __half* r3 = gp + 7 * G3;

  float hp = 0.f;                        // previous h for col c (f32, exact)
  scan_barrier();

#define STEP(TT, PA, PZ, PN, RB, WB, RP)                                    \
  {                                                                         \
    const float ga = __half2float(PA);                                      \
    const float gz = __half2float(PZ);                                      \
    const float gn = __half2float(PN);                                      \
    if ((TT) + 4 < T_) {  /* refill same named regs for TT+4 */             \
      PA = (RP)[o0]; PZ = (RP)[o1]; PN = (RP)[o2];                          \
    }                                                                       \
    RP += 4 * G3;                                                           \
    __half2 aR0 = z2h, aR1 = z2h;                                           \
    __half2 aZ0 = z2h, aZ1 = z2h;                                           \
    __half2 aN0 = initN, aN1 = z2h;                                         \
    _Pragma("unroll")                                                       \
    for (int k = 0; k < 4; ++k) {                                           \
      const uint4 hv = *reinterpret_cast<const uint4*>((RB) + abase + k * 16);\
      const __half2 hx = __builtin_bit_cast(__half2, hv.x);                 \
      const __half2 hy = __builtin_bit_cast(__half2, hv.y);                 \
      const __half2 hz = __builtin_bit_cast(__half2, hv.z);                 \
      const __half2 hw = __builtin_bit_cast(__half2, hv.w);                 \
      aR0 = __hfma2(wgt[0][4 * k + 0], hx, aR0);                            \
      aR1 = __hfma2(wgt[0][4 * k + 1], hy, aR1);                            \
      aR0 = __hfma2(wgt[0][4 * k + 2], hz, aR0);                            \
      aR1 = __hfma2(wgt[0][4 * k + 3], hw, aR1);                            \
      aZ0 = __hfma2(wgt[1][4 * k + 0], hx, aZ0);                            \
      aZ1 = __hfma2(wgt[1][4 * k + 1], hy, aZ1);                            \
      aZ0 = __hfma2(wgt[1][4 * k + 2], hz, aZ0);                            \
      aZ1 = __hfma2(wgt[1][4 * k + 3], hw, aZ1);                            \
      aN0 = __hfma2(wgt[2][4 * k + 0], hx, aN0);                            \
      aN1 = __hfma2(wgt[2][4 * k + 1], hy, aN1);                            \
      aN0 = __hfma2(wgt[2][4 * k + 2], hz, aN0);                            \
      aN1 = __hfma2(wgt[2][4 * k + 3], hw, aN1);                            \
    }                                                                       \
    const __half2 sR = __hadd2(aR0, aR1);                                   \
    const __half2 sZ = __hadd2(aZ0, aZ1);                                   \
    const __half2 sN = __hadd2(aN0, aN1);                                   \
    const float aRs = __low2float(sR) + __high2float(sR);                   \
    const float aZs = __low2float(sZ) + __high2float(sZ);                   \
    const float aNs = __low2float(sN) + __high2float(sN);                   \
    const float fR = dpp_xor_add<0x4E>(dpp_xor_add<0xB1>(aRs));             \
    const float fZ = dpp_xor_add<0x4E>(dpp_xor_add<0xB1>(aZs));             \
    const float fN = dpp_xor_add<0x4E>(dpp_xor_add<0xB1>(aNs));             \
    const float er = fexp2(fmaf(ga, -SC_RZ, fR));                           \
    const float rg = frcp(1.f + er);                                        \
    const float en = fexp2(fmaf(gn, -SC_N, rg * fN));                       \
    const float ez = fexp2(fmaf(gz, -SC_RZ, fZ));                           \
    const float num = fmaf(hp, en, hp) + fmaf(-ez, en, ez);                 \
    const float den = fmaf(ez, en, 1.f + ez + en);                          \
    const float h = num * frcp(den);                                        \
    hp = h;                                                                 \
    if (kq == 0) {                                                          \
      po[(size_t)(TT) * H_] = h;                                            \
      *reinterpret_cast<__half*>((WB) + woff) = __float2half(h);            \
    }                                                                       \
    scan_barrier();                                                         \
  }

  for (int t = 0; t < T_; t += 4) {
    STEP(t,     pa0, pz0, pn0, hA, hB, r0)
    STEP(t + 1, pa1, pz1, pn1, hB, hA, r1)
    STEP(t + 2, pa2, pz2, pn2, hA, hB, r2)
    STEP(t + 3, pa3, pz3, pn3, hB, hA, r3)
  }
#undef STEP
}

// ---------------------------------------------------------------------------
// Kernel 3: y = h @ w_proj.T + b_proj, then LayerNorm. In-place on io.
// ---------------------------------------------------------------------------
#define PROJ_ROWS 64
__global__ __launch_bounds__(64, 1) void proj_ln(
    float* __restrict__ io, const float* __restrict__ w_proj,
    const float* __restrict__ b_proj, const float* __restrict__ gamma,
    const float* __restrict__ beta) {
  const int lane = threadIdx.x;
  const int row0 = blockIdx.x * PROJ_ROWS;
  const int jA = lane, jB = lane + 64;

  unsigned int wa[64], wb[64];
#pragma unroll
  for (int k = 0; k < 64; ++k) {
    float2 v = reinterpret_cast<const float2*>(w_proj + (size_t)jA * H_)[k];
    wa[k] = pack2(v.x, v.y);
  }
#pragma unroll
  for (int k = 0; k < 64; ++k) {
    float2 v = reinterpret_cast<const float2*>(w_proj + (size_t)jB * H_)[k];
    wb[k] = pack2(v.x, v.y);
  }
  const float bA = b_proj[jA], bB = b_proj[jB];
  const float gmA = gamma[jA], gmB = gamma[jB];
  const float btA = beta[jA], btB = beta[jB];

  __shared__ alignas(16) unsigned int hbuf[64];  // 128 halves: one row

  for (int r = 0; r < PROJ_ROWS; ++r) {
    float* rowp = io + (size_t)(row0 + r) * H_;
    float2 v = reinterpret_cast<float2*>(rowp)[lane];
    hbuf[lane] = pack2(v.x, v.y);
    wave_lds_fence();

    float aA = bA, aB = bB;
    const uint4* hp = reinterpret_cast<const uint4*>(hbuf);
#pragma unroll
    for (int k = 0; k < 16; ++k) {
      uint4 hv = hp[k];
      aA = fdot2(wa[4 * k + 0], hv.x, aA);
      aA = fdot2(wa[4 * k + 1], hv.y, aA);
      aA = fdot2(wa[4 * k + 2], hv.z, aA);
      aA = fdot2(wa[4 * k + 3], hv.w, aA);
      aB = fdot2(wb[4 * k + 0], hv.x, aB);
      aB = fdot2(wb[4 * k + 1], hv.y, aB);
      aB = fdot2(wb[4 * k + 2], hv.z, aB);
      aB = fdot2(wb[4 * k + 3], hv.w, aB);
    }

    float s = aA + aB;
    float q = aA * aA + aB * aB;
#pragma unroll
    for (int m = 1; m < 64; m <<= 1) {
      s += __shfl_xor(s, m, 64);
      q += __shfl_xor(q, m, 64);
    }
    const float mu = s * (1.f / 128.f);
    const float var = q * (1.f / 128.f) - mu * mu;
    const float rs = rsqrtf(var + 1e-5f);
    rowp[lane]      = (aA - mu) * rs * gmA + btA;
    rowp[lane + 64] = (aB - mu) * rs * gmB + btB;
    wave_lds_fence();
  }
}

// ---------------------------------------------------------------------------
extern "C" void kernel_launch(void* const* d_in, const int* in_sizes, int n_in,
                              void* d_out, int out_size, void* d_ws, size_t ws_size,
                              hipStream_t stream) {
  const float* x      = (const float*)d_in[0];
  const float* w_ih   = (const float*)d_in[1];
  const float* w_hh   = (const float*)d_in[2];
  const float* b_ih   = (const float*)d_in[3];
  const float* b_hh   = (const float*)d_in[4];
  const float* w_proj = (const float*)d_in[5];
  const float* b_proj = (const float*)d_in[6];
  const float* gamma  = (const float*)d_in[7];
  const float* beta   = (const float*)d_in[8];

  float* out = (float*)d_out;
  __half* gi = (__half*)d_ws;            // [B*T][384] f16 = 48 MB scratch

  gi_gemm<<<512, 384, 0, stream>>>(x, w_ih, b_ih, b_hh, gi);
  gru_scan<<<B_, 512, 0, stream>>>(gi, w_hh, b_hh, out);
  proj_ln<<<(B_ * T_) / PROJ_ROWS, 64, 0, stream>>>(out, w_proj, b_proj, gamma, beta);
}

// Round 13
// 2250.335 us; speedup vs baseline: 1.1184x; 1.1184x over previous
//
#include <hip/hip_runtime.h>
#include <hip/hip_fp16.h>

#define B_   16
#define T_   4096
#define DIN  256
#define H_   128
#define G3   384   // 3*H

// exponent prescales: sigmoid -> rcp(1+exp2(-log2e * x)), tanh via sigmoid(2x)
#define SC_RZ 1.4426950408889634f
#define SC_N  2.8853900817779268f

typedef _Float16 half2_t __attribute__((ext_vector_type(2)));

__device__ __forceinline__ float fdot2(unsigned int a, unsigned int b, float c) {
#if __has_builtin(__builtin_amdgcn_fdot2)
  return __builtin_amdgcn_fdot2(__builtin_bit_cast(half2_t, a),
                                __builtin_bit_cast(half2_t, b), c, false);
#else
  const __half2 ha = __builtin_bit_cast(__half2, a);
  const __half2 hb = __builtin_bit_cast(__half2, b);
  return c + __half2float(__low2half(ha)) * __half2float(__low2half(hb))
           + __half2float(__high2half(ha)) * __half2float(__high2half(hb));
#endif
}

// Cross-lane add via DPP quad_perm (pure VALU — no LDS pipe):
// CTRL 0xB1 = quad_perm [1,0,3,2] (lane^1).
template <int CTRL>
__device__ __forceinline__ float dpp_xor_add(float x) {
  const int yi = __builtin_amdgcn_mov_dpp(__builtin_bit_cast(int, x),
                                          CTRL, 0xF, 0xF, true);
  return x + __builtin_bit_cast(float, yi);
}

__device__ __forceinline__ unsigned int pack2(float x, float y) {
  __half2 h = __floats2half2_rn(x, y);
  return __builtin_bit_cast(unsigned int, h);
}

__device__ __forceinline__ float fexp2(float x) {
#if __has_builtin(__builtin_amdgcn_exp2f)
  return __builtin_amdgcn_exp2f(x);
#else
  return exp2f(x);
#endif
}
__device__ __forceinline__ float frcp(float x) {
#if __has_builtin(__builtin_amdgcn_rcpf)
  return __builtin_amdgcn_rcpf(x);
#else
  return 1.f / x;
#endif
}

// lgkmcnt-only barrier: LDS ordering without draining global loads/stores.
__device__ __forceinline__ void scan_barrier() {
  asm volatile("s_waitcnt lgkmcnt(0)" ::: "memory");
  __builtin_amdgcn_s_barrier();
  asm volatile("" ::: "memory");
}

__device__ __forceinline__ void barrier_lds() {
  asm volatile("s_waitcnt lgkmcnt(0)" ::: "memory");
  __builtin_amdgcn_s_barrier();
  asm volatile("" ::: "memory");
}

__device__ __forceinline__ void wave_lds_fence() {
  asm volatile("s_waitcnt lgkmcnt(0)" ::: "memory");
}

// ---------------------------------------------------------------------------
// Kernel 1: gi[r, j] = f16( b_ih[j] + (j<256 ? b_hh[j] : 0) + dot(x,w_ih[j]) )
// b_hh fold legal ONLY for r,z rows (b_hn stays under r in the scan).
// Dots via v_pk_fma_f16 (2 cyc/instr vs fdot2's ~6): 4 staggered f16x2 accs,
// f16-accum impact on final absmax ≈ +0.001 (R8 vs R9 evidence).
// ---------------------------------------------------------------------------
__global__ __launch_bounds__(384, 1) void gi_gemm(
    const float* __restrict__ x, const float* __restrict__ w_ih,
    const float* __restrict__ b_ih, const float* __restrict__ b_hh,
    __half* __restrict__ gi) {
  const int j = threadIdx.x;             // 0..383 : output gate-row
  const int rbase = blockIdx.x * 128;    // 128 x-rows per block

  __half2 wreg[128];                     // 256 halves = w_ih row j
  const float* wrow = w_ih + (size_t)j * DIN;
#pragma unroll
  for (int k = 0; k < 128; ++k) {
    float2 w2 = reinterpret_cast<const float2*>(wrow)[k];
    wreg[k] = __floats2half2_rn(w2.x, w2.y);
  }
  const float bias = b_ih[j] + ((j < 256) ? b_hh[j] : 0.f);
  const __half2 z2h = __floats2half2_rn(0.f, 0.f);

  __shared__ alignas(16) unsigned int xs[16 * 128];  // 16 rows x 256 halves

  for (int c = 0; c < 8; ++c) {          // 8 chunks of 16 rows
    barrier_lds();                       // protect xs vs previous chunk reads
    const int row0 = rbase + c * 16;
    for (int i = j; i < 16 * 128; i += 384) {
      const int r = i >> 7, col = i & 127;
      float2 v = reinterpret_cast<const float2*>(x + (size_t)(row0 + r) * DIN)[col];
      xs[i] = pack2(v.x, v.y);
    }
    barrier_lds();
    for (int r = 0; r < 16; ++r) {
      __half2 a0 = z2h, a1 = z2h, a2 = z2h, a3 = z2h;
      const uint4* hp = reinterpret_cast<const uint4*>(xs + r * 128);
#pragma unroll
      for (int k = 0; k < 32; ++k) {
        uint4 hv = hp[k];                // uniform addr -> LDS broadcast
        a0 = __hfma2(wreg[4 * k + 0], __builtin_bit_cast(__half2, hv.x), a0);
        a1 = __hfma2(wreg[4 * k + 1], __builtin_bit_cast(__half2, hv.y), a1);
        a2 = __hfma2(wreg[4 * k + 2], __builtin_bit_cast(__half2, hv.z), a2);
        a3 = __hfma2(wreg[4 * k + 3], __builtin_bit_cast(__half2, hv.w), a3);
      }
      const __half2 s2 = __hadd2(__hadd2(a0, a1), __hadd2(a2, a3));
      const float acc = bias + __low2float(s2) + __high2float(s2);
      gi[(size_t)(row0 + r) * G3 + j] = __float2half(acc);
    }
  }
}

// ---------------------------------------------------------------------------
// Kernel 2: GRU scan. 16 blocks (1/batch) x 256 threads (4 waves, 1/SIMD —
// per-SIMD issue = one wave's instructions; minimal barrier skew).
// Lane (w, l): col c = w*32 + (l>>1), K-half = l&1 (partner adjacent -> ONE
// DPP ^1 hop per gate). Dots: 96 v_pk_fma_f16 @ 2 cyc (f16 accum — proven
// precision-neutral in R12: absmax identical to f32 path). h f16 in
// double-buffered LDS, halves staggered 144 B (conflict-free, R7-proven).
// b_hn folded into n-acc init of even lanes (exact once per pair). Merged
// gate algebra, er/ez exp2 issued in parallel. One lgkm-only barrier/step;
// gi prefetched 4 steps deep in statically-named registers.
// ---------------------------------------------------------------------------
__global__ __launch_bounds__(256, 1) void gru_scan(
    const __half* __restrict__ gi, const float* __restrict__ w_hh,
    const float* __restrict__ b_hh, float* __restrict__ out) {
  const int b   = blockIdx.x;
  const int tid = threadIdx.x;
  const int l   = tid & 63;
  const int w   = tid >> 6;              // wave 0..3
  const int half = l & 1;                // K-half 0/1 (partner = l^1)
  const int c   = w * 32 + (l >> 1);     // hidden column 0..127

  // Weights: rows {c, 128+c, 256+c}, K-range [half*64, half*64+64), f16x2,
  // prescaled by -log2e (r,z) / -2log2e (n).
  __half2 wgt[3][32];
#pragma unroll
  for (int g = 0; g < 3; ++g) {
    const float sg = (g < 2) ? -SC_RZ : -SC_N;
    const float* row = w_hh + (size_t)(g * H_ + c) * H_ + half * 64;
#pragma unroll
    for (int k = 0; k < 32; ++k) {
      float2 a = reinterpret_cast<const float2*>(row)[k];
      wgt[g][k] = __floats2half2_rn(a.x * sg, a.y * sg);
    }
  }
  // scaled b_hn, folded into the n-acc init of the even lane (once per pair).
  const float bnS = b_hh[2 * H_ + c] * -SC_N;
  const __half2 initN = __floats2half2_rn((half == 0) ? bnS : 0.f, 0.f);
  const __half2 z2h = __floats2half2_rn(0.f, 0.f);

  // h buffers (f16): half0 = h[0..63] at bytes 0..127; half1 at bytes
  // 144..271 (144 B stagger -> 2 broadcast addrs hit disjoint banks).
  __shared__ alignas(16) char hA[288];
  __shared__ alignas(16) char hB[288];
  if (tid < 72) reinterpret_cast<unsigned int*>(hA)[tid] = 0u;  // h0 = 0

  const int abase = half * 144;          // this lane's K-half read base
  const int woff  = (c < 64) ? (c * 2) : (144 + (c - 64) * 2);

  const __half* gp = gi + (size_t)b * T_ * G3;
  float* po = out + ((size_t)b * T_) * H_ + c;
  const int o0 = c, o1 = H_ + c, o2 = 2 * H_ + c;

  // 4-deep prefetch: raw __half regs (convert at use), statically named.
  __half pa0 = gp[o0],          pz0 = gp[o1],          pn0 = gp[o2];
  __half pa1 = gp[G3 + o0],     pz1 = gp[G3 + o1],     pn1 = gp[G3 + o2];
  __half pa2 = gp[2 * G3 + o0], pz2 = gp[2 * G3 + o1], pn2 = gp[2 * G3 + o2];
  __half pa3 = gp[3 * G3 + o0], pz3 = gp[3 * G3 + o1], pn3 = gp[3 * G3 + o2];
  const __half* r0 = gp + 4 * G3;        // refill sources, one per phase
  const __half* r1 = gp + 5 * G3;
  const __half* r2 = gp + 6 * G3;
  const __half* r3 = gp + 7 * G3;

  float hp = 0.f;                        // previous h for col c (f32, exact)
  scan_barrier();

#define STEP(TT, PA, PZ, PN, RB, WB, RP)                                    \
  {                                                                         \
    const float ga = __half2float(PA);                                      \
    const float gz = __half2float(PZ);                                      \
    const float gn = __half2float(PN);                                      \
    if ((TT) + 4 < T_) {  /* refill same named regs for TT+4 */             \
      PA = (RP)[o0]; PZ = (RP)[o1]; PN = (RP)[o2];                          \
    }                                                                       \
    RP += 4 * G3;                                                           \
    __half2 aR0 = z2h, aR1 = z2h;                                           \
    __half2 aZ0 = z2h, aZ1 = z2h;                                           \
    __half2 aN0 = initN, aN1 = z2h;                                         \
    _Pragma("unroll")                                                       \
    for (int k = 0; k < 8; ++k) {                                           \
      const uint4 hv = *reinterpret_cast<const uint4*>((RB) + abase + k * 16);\
      const __half2 hx = __builtin_bit_cast(__half2, hv.x);                 \
      const __half2 hy = __builtin_bit_cast(__half2, hv.y);                 \
      const __half2 hz = __builtin_bit_cast(__half2, hv.z);                 \
      const __half2 hw = __builtin_bit_cast(__half2, hv.w);                 \
      aR0 = __hfma2(wgt[0][4 * k + 0], hx, aR0);                            \
      aR1 = __hfma2(wgt[0][4 * k + 1], hy, aR1);                            \
      aR0 = __hfma2(wgt[0][4 * k + 2], hz, aR0);                            \
      aR1 = __hfma2(wgt[0][4 * k + 3], hw, aR1);                            \
      aZ0 = __hfma2(wgt[1][4 * k + 0], hx, aZ0);                            \
      aZ1 = __hfma2(wgt[1][4 * k + 1], hy, aZ1);                            \
      aZ0 = __hfma2(wgt[1][4 * k + 2], hz, aZ0);                            \
      aZ1 = __hfma2(wgt[1][4 * k + 3], hw, aZ1);                            \
      aN0 = __hfma2(wgt[2][4 * k + 0], hx, aN0);                            \
      aN1 = __hfma2(wgt[2][4 * k + 1], hy, aN1);                            \
      aN0 = __hfma2(wgt[2][4 * k + 2], hz, aN0);                            \
      aN1 = __hfma2(wgt[2][4 * k + 3], hw, aN1);                            \
    }                                                                       \
    const __half2 sR = __hadd2(aR0, aR1);                                   \
    const __half2 sZ = __hadd2(aZ0, aZ1);                                   \
    const __half2 sN = __hadd2(aN0, aN1);                                   \
    const float aRs = __low2float(sR) + __high2float(sR);                   \
    const float aZs = __low2float(sZ) + __high2float(sZ);                   \
    const float aNs = __low2float(sN) + __high2float(sN);                   \
    const float fR = dpp_xor_add<0xB1>(aRs);                                \
    const float fZ = dpp_xor_add<0xB1>(aZs);                                \
    const float fN = dpp_xor_add<0xB1>(aNs);                                \
    const float er = fexp2(fmaf(ga, -SC_RZ, fR));                           \
    const float ez = fexp2(fmaf(gz, -SC_RZ, fZ));  /* parallel with er */   \
    const float rg = frcp(1.f + er);                                        \
    const float en = fexp2(fmaf(gn, -SC_N, rg * fN));                       \
    const float num = fmaf(hp, en, hp) + fmaf(-ez, en, ez);                 \
    const float den = fmaf(ez, en, 1.f + ez + en);                          \
    const float h = num * frcp(den);                                        \
    hp = h;                                                                 \
    if (half == 0) {                                                        \
      po[(size_t)(TT) * H_] = h;                                            \
      *reinterpret_cast<__half*>((WB) + woff) = __float2half(h);            \
    }                                                                       \
    scan_barrier();                                                         \
  }

  for (int t = 0; t < T_; t += 4) {
    STEP(t,     pa0, pz0, pn0, hA, hB, r0)
    STEP(t + 1, pa1, pz1, pn1, hB, hA, r1)
    STEP(t + 2, pa2, pz2, pn2, hA, hB, r2)
    STEP(t + 3, pa3, pz3, pn3, hB, hA, r3)
  }
#undef STEP
}

// ---------------------------------------------------------------------------
// Kernel 3: y = h @ w_proj.T + b_proj, then LayerNorm. In-place on io.
// ---------------------------------------------------------------------------
#define PROJ_ROWS 64
__global__ __launch_bounds__(64, 1) void proj_ln(
    float* __restrict__ io, const float* __restrict__ w_proj,
    const float* __restrict__ b_proj, const float* __restrict__ gamma,
    const float* __restrict__ beta) {
  const int lane = threadIdx.x;
  const int row0 = blockIdx.x * PROJ_ROWS;
  const int jA = lane, jB = lane + 64;

  unsigned int wa[64], wb[64];
#pragma unroll
  for (int k = 0; k < 64; ++k) {
    float2 v = reinterpret_cast<const float2*>(w_proj + (size_t)jA * H_)[k];
    wa[k] = pack2(v.x, v.y);
  }
#pragma unroll
  for (int k = 0; k < 64; ++k) {
    float2 v = reinterpret_cast<const float2*>(w_proj + (size_t)jB * H_)[k];
    wb[k] = pack2(v.x, v.y);
  }
  const float bA = b_proj[jA], bB = b_proj[jB];
  const float gmA = gamma[jA], gmB = gamma[jB];
  const float btA = beta[jA], btB = beta[jB];

  __shared__ alignas(16) unsigned int hbuf[64];  // 128 halves: one row

  for (int r = 0; r < PROJ_ROWS; ++r) {
    float* rowp = io + (size_t)(row0 + r) * H_;
    float2 v = reinterpret_cast<float2*>(rowp)[lane];
    hbuf[lane] = pack2(v.x, v.y);
    wave_lds_fence();

    float aA = bA, aB = bB;
    const uint4* hp = reinterpret_cast<const uint4*>(hbuf);
#pragma unroll
    for (int k = 0; k < 16; ++k) {
      uint4 hv = hp[k];
      aA = fdot2(wa[4 * k + 0], hv.x, aA);
      aA = fdot2(wa[4 * k + 1], hv.y, aA);
      aA = fdot2(wa[4 * k + 2], hv.z, aA);
      aA = fdot2(wa[4 * k + 3], hv.w, aA);
      aB = fdot2(wb[4 * k + 0], hv.x, aB);
      aB = fdot2(wb[4 * k + 1], hv.y, aB);
      aB = fdot2(wb[4 * k + 2], hv.z, aB);
      aB = fdot2(wb[4 * k + 3], hv.w, aB);
    }

    float s = aA + aB;
    float q = aA * aA + aB * aB;
#pragma unroll
    for (int m = 1; m < 64; m <<= 1) {
      s += __shfl_xor(s, m, 64);
      q += __shfl_xor(q, m, 64);
    }
    const float mu = s * (1.f / 128.f);
    const float var = q * (1.f / 128.f) - mu * mu;
    const float rs = rsqrtf(var + 1e-5f);
    rowp[lane]      = (aA - mu) * rs * gmA + btA;
    rowp[lane + 64] = (aB - mu) * rs * gmB + btB;
    wave_lds_fence();
  }
}

// ---------------------------------------------------------------------------
extern "C" void kernel_launch(void* const* d_in, const int* in_sizes, int n_in,
                              void* d_out, int out_size, void* d_ws, size_t ws_size,
                              hipStream_t stream) {
  const float* x      = (const float*)d_in[0];
  const float* w_ih   = (const float*)d_in[1];
  const float* w_hh   = (const float*)d_in[2];
  const float* b_ih   = (const float*)d_in[3];
  const float* b_hh   = (const float*)d_in[4];
  const float* w_proj = (const float*)d_in[5];
  const float* b_proj = (const float*)d_in[6];
  const float* gamma  = (const float*)d_in[7];
  const float* beta   = (const float*)d_in[8];

  float* out = (float*)d_out;
  __half* gi = (__half*)d_ws;            // [B*T][384] f16 = 48 MB scratch

  gi_gemm<<<512, 384, 0, stream>>>(x, w_ih, b_ih, b_hh, gi);
  gru_scan<<<B_, 256, 0, stream>>>(gi, w_hh, b_hh, out);
  proj_ln<<<(B_ * T_) / PROJ_ROWS, 64, 0, stream>>>(out, w_proj, b_proj, gamma, beta);
}